// Round 6
// baseline (97.994 us; speedup 1.0000x reference)
//
#include <hip/hip_runtime.h>
#include <hip/hip_bf16.h>
#include <math.h>

// Problem: P=20000, d=128, C=512, h=4 (fixed dataset). d==128, h==4, C==512 assumed.
#define D_DIM 128
#define H_DIM 4

typedef __attribute__((ext_vector_type(4))) float f32x4;
typedef __attribute__((ext_vector_type(8))) __bf16 bf16x8v;

__device__ inline unsigned short f2bf(float f) {
    __hip_bfloat16 b = __float2bfloat16(f);
    return *reinterpret_cast<unsigned short*>(&b);
}

// ---- fused prep: K-row norms (bf16) + Theta-slot norms (bf16+fp32) + inits ----
// grid = Ppad/4 blocks (5024). Blocks [0, NJ/4) additionally handle Theta.
__global__ __launch_bounds__(256) void k_prep(
    const float* __restrict__ K, unsigned int* __restrict__ Knb,
    float* __restrict__ rnK,
    const float* __restrict__ Theta, unsigned int* __restrict__ Tnb,
    float* __restrict__ Tn32,
    const float* __restrict__ initial, float* __restrict__ out,
    int* __restrict__ head_of, int* __restrict__ done,
    int P, int Ppad, int NJ)
{
    int wave = threadIdx.x >> 6, lane = threadIdx.x & 63;
    if (blockIdx.x == 0 && threadIdx.x == 0) *done = 0;

    int row = blockIdx.x * 4 + wave;
    if (row < Ppad) {
        if (row >= P) {
            Knb[(size_t)row * 64 + lane] = 0u;
        } else {
            float2 v = ((const float2*)(K + (size_t)row * D_DIM))[lane];
            float ss = v.x * v.x + v.y 
* v.y;
            #pragma unroll
            for (int off = 1; off < 64; off <<= 1) ss += __shfl_xor(ss, off);
            float rn = 1.0f / fmaxf(sqrtf(ss), 1e-12f);
            unsigned int pk = (unsigned)f2bf(v.x * rn) | ((unsigned)f2bf(v.y * rn) << 16);
            Knb[(size_t)row * 64 + lane] = pk;
            if (lane == 0) {
                rnK[row] = rn;
                out[row] = initial[row];
                head_of[row] = 0x7FFFFFFF;
            }
        }
    }

    if (blockIdx.x < (NJ >> 2)) {
        int j = blockIdx.x * 4 + wave;
        int c = j >> 2, s = j & 3;
        const float* base = Theta + (size_t)c * (D_DIM * H_DIM) + s;
        float t0 = base[(2 * lane) * H_DIM];
        float t1 = base[(2 * lane + 1) * H_DIM];
        float ss = t0 * t0 + t1 * t1;
        #pragma unroll
        for (int off = 1; off < 64; off <<= 1) ss += __shfl_xor(ss, off);
        float rn = 1.0f / fmaxf(sqrtf(ss), 1e-12f);
        float n0 = t0 * rn, n1 = t1 * rn;
        Tnb[(size_t)j * 64 + lane] = (unsigned)f2bf(n0) | ((unsigned)f2bf(n1) << 16);
        float2 w; w.x = n0; w.y = n1;
        ((float2*)(Tn32 + (size_t)j * D_DIM))[lane] = w;
    }
}

// ---- bf16 MFMA GEMM, fused per-(j, 32p-chunk) max; XCD-swizzled 1D grid ----
// grid = NT*16 blocks.  Also folds the head_of scatter (block 0).
__global__ __launch_bounds__(256) void k_mfma_max(
    const unsigned short* __restrict__ Knb, const unsigned short* __restrict__ Tnb,
    float* __restrict__ pv2, const int* __restrict__ head_idx,
    int* __restrict__ head_of, int C, int NT4, int NBLK)
{
    __shared__ __align__(16) unsigned short As[128 * 128];  // Tn tile  32 KB
    __shared__ __align__(16) unsigned short Bs[128 * 128];  // Kn tile  32 KB

    int tid = threadIdx.x;
    int orig = blockIdx.x;
    if (orig == 0) {
        for (int g = tid; g < C; g += 256) atomicMin(&head_of[head_idx[g]], g);
    }
    // bijective XCD swizzle: each XCD gets a contiguous wgid range; wgid = p*16 + j
    int q = NBLK >> 3, r = NBLK & 7;
    int xcd = orig & 7, idx = orig >> 3;
    int wgid = (xcd < r ? xcd * (q + 1) : r * (q + 1) + (xcd - r) * q) + idx;
    int pt = wgid >> 4, jt = wgid & 15;
    int p0 = pt * 128, j0 = jt * 128;
    int lane = tid & 63;
    int wave = tid >> 6;

    // stage via global_load_lds: linear LDS dest, inverse-XOR-swizzled global src.
    {
        int rr = lane >> 4, cc = lane & 15;
        const unsigned short* gA = Tnb + (size_t)j0 * 128;
        const unsigned short* gB = Knb + (size_t)p0 * 128;
        #pragma unroll
        for (int i = 0; i < 8; i++) {
            int r0 = wave * 32 + i * 4;
            int rw = r0 + rr;
            int sc = (cc ^ (rw & 7)) << 3;
            __builtin_amdgcn_global_load_lds(
                (const __attribute__((address_space(1))) unsigned int*)(gA + (size_t)rw * 128 + sc),
                (__attribute__((address_space(3))) unsigned int*)&As[r0 * 128], 16, 0, 0);
            __builtin_amdgcn_global_load_lds(
                (const __attribute__((address_space(1))) unsigned int*)(gB + (size_t)rw * 128 + sc),
                (__attribute__((address_space(3))) unsigned int*)&Bs[r0 * 128], 16, 0, 0);
        }
    }
    __syncthreads();

    int wm = wave >> 1, wn = wave & 1;
    int lr = lane & 15, lg = lane >> 4;

    f32x4 acc[4][4];
    #pragma unroll
    for (int m = 0; m < 4; m++)
        #pragma unroll
        for (int n = 0; n < 4; n++) { f32x4 z = {0.f, 0.f, 0.f, 0.f}; acc[m][n] = z; }

    #pragma unroll
    for (int ks = 0; ks < 4; ks++) {
        int koff = (8 * lg + 32 * ks) ^ ((lr & 7) << 3);
        bf16x8v af[4], bv[4];
        #pragma unroll
        for (int m = 0; m < 4; m++) {
            int row = 64 * wm + 16 * m + lr;
            af[m] = *(const bf16x8v*)&As[row * 128 + koff];
        }
        #pragma unroll
        for (int n = 0; n < 4; n++) {
            int row = 64 * wn + 16 * n + lr;
            bv[n] = *(const bf16x8v*)&Bs[row * 128 + koff];
        }
        #pragma unroll
        for (int m = 0; m < 4; m++)
            #pragma unroll
            for (int n = 0; n < 4; n++)
                acc[m][n] = __builtin_amdgcn_mfma_f32_16x16x32_bf16(af[m], bv[n], acc[m][n], 0, 0, 0);
    }

    // epilogue: per-32p-chunk max.  C/D: col(p)=lane&15, row(j)=4*(lane>>4)+reg
    __syncthreads();
    float* red = (float*)As;   // [128 j][4 chunk]
    #pragma unroll
    for (int m = 0; m < 4; m++) {
        #pragma unroll
        for (int n2 = 0; n2 < 2; n2++) {
            f32x4 a0 = acc[m][2 * n2], a1 = acc[m][2 * n2 + 1];
            float t0 = fmaxf(a0[0], a1[0]);
            float t1 = fmaxf(a0[1], a1[1]);
            float t2 = fmaxf(a0[2], a1[2]);
            float t3 = fmaxf(a0[3], a1[3]);
            #pragma unroll
            for (int off = 1; off <= 8; off <<= 1) {
                t0 = fmaxf(t0, __shfl_xor(t0, off));
                t1 = fmaxf(t1, __shfl_xor(t1, off));
                t2 = fmaxf(t2, __shfl_xor(t2, off));
                t3 = fmaxf(t3, __shfl_xor(t3, off));
            }
            if (lr == 0) {
                int jb = 64 * wm + 16 * m + 4 * lg;
                int ch = 2 * wn + n2;
                red[(jb + 0) * 4 + ch] = t0;
                red[(jb + 1) * 4 + ch] = t1;
                red[(jb + 2) * 4 + ch] = t2;
                red[(jb + 3) * 4 + ch] = t3;
            }
        }
    }
    __syncthreads();
    #pragma unroll
    for (int e = tid; e < 512; e += 256) {
        int jl = e >> 2, ch = e & 3;
        pv2[(size_t)(j0 + jl) * NT4 + pt * 4 + ch] = red[jl * 4 + ch];
    }
}

// ---- fused prune (threshold + exact fp32 rescore) + last-block soft-logic ----
// grid = NJ/4 = 512 blocks x 256.  Last finished block runs the 6-iter logic.
__global__ __launch_bounds__(256) void k_prune_logic(
    const float* __restrict__ pv2, const float* __restrict__ K,
    const float* __restrict__ rnK, const float* __restrict__ Tn32,
    float* __restrict__ conf, int* __restrict__ best, int* __restrict__ done,
    const int* __restrict__ head_idx, const float* __restrict__ initial_val,
    const int* __restrict__ head_of, float* __restrict__ out,
    int P, int NT4, int C, int NB)
{
    __shared__ float hval[512];
    __shared__ float elds[512];
    __shared__ int isLast;

    int wave = threadIdx.x >> 6, lane = threadIdx.x & 63;
    int j = blockIdx.x * 4 + wave;
    const float* row = pv2 + (size_t)j * NT4;

    // single pass: load all chunk maxes (NT4=628 <= 640) and reduce
    float v[10];
    float m = -INFINITY;
    #pragma unroll
    for (int i = 0; i < 10; i++) {
        int t = lane + i * 64;
        v[i] = (t < NT4) ? row[t] : -INFINITY;
        m = fmaxf(m, v[i]);
    }
    #pragma unroll
    for (int off = 32; off; off >>= 1) m = fmaxf(m, __shfl_xor(m, off));
    float thr = m - 0.009f;   // 2*eps bf16 unit-vector dot bound

    float bv = -INFINITY; int bbp = 0x7FFFFFFF;
    int half = lane & 1;      // which 64-elem half of the d-dim
    int pl = lane >> 1;       // p within chunk (0..31)
    #pragma unroll
    for (int i = 0; i < 10; i++) {
        unsigned long long ball = __ballot(v[i] >= thr);   // wave-uniform
        while (ball) {
            int bit = __ffsll(ball) - 1;
            ball &= ball - 1;
            int t = i * 64 + bit;
            int p = t * 32 + pl;
            bool ok = (p < P);
            int pc = ok ? p : 0;
            const float4* kp = (const float4*)(K + (size_t)pc * D_DIM + half * 64);
            const float4* tp = (const float4*)(Tn32 + (size_t)j * D_DIM + half * 64);
            float sx = 0.f, sy = 0.f, sz = 0.f, sw = 0.f;
            #pragma unroll
            for (int k4 = 0; k4 < 16; k4++) {
                float4 a = kp[k4], b = tp[k4];
                sx = fmaf(a.x, b.x, sx); sy = fmaf(a.y, b.y, sy);
                sz = fmaf(a.z, b.z, sz); sw = fmaf(a.w, b.w, sw);
            }
            float dot = (sx + sy) + (sz + sw);
            dot += __shfl_xor(dot, 1);      // combine d-halves
            float vv = ok ? dot * rnK[pc] : -INFINITY;
            int bp = p;
            #pragma unroll
            for (int off = 2; off < 64; off <<= 1) {
                float ov = __shfl_xor(vv, off);
                int op = __shfl_xor(bp, off);
                if (ov > vv || (ov == vv && op < bp)) { vv = ov; bp = op; }
            }
            if (vv > bv || (vv == bv && bp < bbp)) { bv = vv; bbp = bp; }
        }
    }
    if (lane == 0) {
        __hip_atomic_store(&conf[j], bv, __ATOMIC_RELAXED, __HIP_MEMORY_SCOPE_AGENT);
        __hip_atomic_store(&best[j], bbp, __ATOMIC_RELAXED, __HIP_MEMORY_SCOPE_AGENT);
    }
    __syncthreads();
    if (threadIdx.x == 0) {
        __threadfence();
        int r = __hip_atomic_fetch_add(done, 1, __ATOMIC_ACQ_REL, __HIP_MEMORY_SCOPE_AGENT);
        isLast = (r == NB - 1);
    }
    __syncthreads();
    if (!isLast) return;

    // ---- logic phase: 256 threads, 2 clauses each (C==512) ----
    int tid = threadIdx.x;
    int cc[2] = { tid, tid + 256 };
    int hh[2], ms[2];
    float cf[2][H_DIM], v0[2][H_DIM]; int bs[2][H_DIM];
    #pragma unroll
    for (int u = 0; u < 2; u++) {
        hh[u] = head_idx[cc[u]];
        ms[u] = head_of[hh[u]];
        hval[cc[u]] = initial_val[hh[u]];
        #pragma unroll
        for (int s = 0; s < H_DIM; s++) {
            int jj = cc[u] * H_DIM + s;
            cf[u][s] = __hip_atomic_load(&conf[jj], __ATOMIC_RELAXED, __HIP_MEMORY_SCOPE_AGENT);
            int b = __hip_atomic_load(&best[jj], __ATOMIC_RELAXED, __HIP_MEMORY_SCOPE_AGENT);
            v0[u][s] = initial_val[b];
            int ho = head_of[b];
            bs[u][s] = (ho < C) ? ho : -1;
        }
    }
    __syncthreads();

    const float inv_tau = 20.0f;            // 1/TAU
    const float logn = logf(2.0f * H_DIM);  // log 8
    const float beta = 8.0f;

    for (int it = 0; it < 6; it++) {
        float x[2][2 * H_DIM], cur[2];
        #pragma unroll
        for (int u = 0; u < 2; u++) {
            #pragma unroll
            for (int s = 0; s < H_DIM; s++) {
                x[u][s] = cf[u][s];
                x[u][H_DIM + s] = (bs[u][s] >= 0) ? hval[bs[u][s]] : v0[u][s];
            }
            cur[u] = hval[ms[u]];
        }
        elds[cc[0]] = 0.f; elds[cc[1]] = 0.f;
        __syncthreads();

        #pragma unroll
        for (int u = 0; u < 2; u++) {
            float mm = x[u][0];
            #pragma unroll
            for (int i = 1; i < 2 * H_DIM; i++) mm = fminf(mm, x[u][i]);
            float ssum = 0.f;
            #pragma unroll
            for (int i = 0; i < 2 * H_DIM; i++) ssum += expf((mm - x[u][i]) * inv_tau);
            float g = -inv_tau * ((-mm * inv_tau + logf(ssum)) - logn);
            g = fminf(fmaxf(g, 0.f), 1.f);
            atomicAdd(&elds[ms[u]], expf(beta * g));
        }
        __syncthreads();

        #pragma unroll
        for (int u = 0; u < 2; u++) {
            float e = elds[ms[u]];
            float gh = logf(fmaxf(e, 1e-38f)) / beta;
            float nv = fmaxf(cur[u], gh);
            if (ms[u] == cc[u]) hval[cc[u]] = nv;
        }
        __syncthreads();
    }

    #pragma unroll
    for (int u = 0; u < 2; u++)
        if (ms[u] == cc[u]) out[hh[u]] = hval[cc[u]];
}

// ---------------- launch ----------------
extern "C" void kernel_launch(void* const* d_in, const int* in_sizes, int n_in,
                              void* d_out, int out_size, void* d_ws, size_t ws_size,
                              hipStream_t stream) {
    const float* K        = (const float*)d_in[0];
    const float* Theta    = (const float*)d_in[1];
    const int*   head_idx = (const int*)d_in[2];
    const float* initial  = (const float*)d_in[3];
    float* out = (float*)d_out;

    int P  = in_sizes[3];
    int C  = in_sizes[2];
    int NJ = C * H_DIM;                     // 2048
    int Ppad = ((P + 127) / 128) * 128;     // 20096
    int NT = Ppad / 128;                    // 157
    int NT4 = NT * 4;                       // 628 (32-p chunks)
    int NBLK = NT * (NJ / 128);             // 2512

    char* w = (char*)d_ws;
    size_t off = 0;
    auto alloc = [&](size_t bytes) { void* p = w + off; off += (bytes + 255) & ~(size_t)255; return p; };
    unsigned int* Knb  = (unsigned int*)alloc((size_t)Ppad * D_DIM * 2);
    unsigned int* Tnb  = (unsigned int*)alloc((size_t)NJ * D_DIM * 2);
    float* Tn32 = (float*)alloc((size_t)NJ * D_DIM * 4);
    float* rnK  = (float*)alloc((size_t)P * 4);
    float* pv2  = (float*)alloc((size_t)NJ * NT4 * 4);
    float* conf = (float*)alloc((size_t)NJ * 4);
    int*   best = (int*)alloc((size_t)NJ * 4);
    int* head_of = (int*)alloc((size_t)P * 4);
    int* done = (int*)alloc(256);
    (void)ws_size;

    k_prep<<<Ppad / 4, 256, 0, stream>>>(K, Knb, rnK, Theta, Tnb, Tn32,
                                         initial, out, head_of, done, P, Ppad, NJ);

    k_mfma_max<<<NBLK, 256, 0, stream>>>((const unsigned short*)Knb,
                                         (const unsigned short*)Tnb, pv2,
                                         head_idx, head_of, C, NT4, NBLK);

    k_prune_logic<<<NJ / 4, 256, 0, stream>>>(pv2, K, rnK, Tn32, conf, best, done,
                                              head_idx, initial, head_of, out,
                                              P, NT4, C, NJ / 4);
}

// Round 7
// 77.178 us; speedup vs baseline: 1.2697x; 1.2697x over previous
//
#include <hip/hip_runtime.h>
#include <hip/hip_bf16.h>
#include <math.h>

// Problem: P=20000, d=128, C=512, h=4 (fixed dataset). d==128, h==4, C==512 assumed.
#define D_DIM 128
#define H_DIM 4

typedef __attribute__((ext_vector_type(4))) float f32x4;
typedef __attribute__((ext_vector_type(8))) __bf16 bf16x8v;

__device__ inline unsigned short f2bf(float f) {
    __hip_bfloat16 b = __float2bfloat16(f);
    return *reinterpret_cast<unsigned short*>(&b);
}

// ---- fused prep: K-row norms (bf16) + Theta-slot norms (bf16+fp32) + inits ----
// grid = Ppad/4 blocks (5024). Blocks [0, NJ/4) additionally handle Theta.
__global__ __launch_bounds__(256) void k_prep(
    const float* __restrict__ K, unsigned int* __restrict__ Knb,
    float* __restrict__ rnK,
    const float* __restrict__ Theta, unsigned int* __restrict__ Tnb,
    float* __restrict__ Tn32,
    const float* __restrict__ initial, float* __restrict__ out,
    int* __restrict__ head_of, int P, int Ppad, int NJ)
{
    int wave = threadIdx.x >> 6, lane = threadIdx.x & 63;

    int row = blockIdx.x * 4 + wave;
    if (row < Ppad) {
        if (row >= P) {
            Knb[(size_t)row * 64 + lane] = 0u;
        } else {
            float2 v = ((const float2*)(K + (size_t)row * D_DIM))[lane];
            float ss = v.x * v.x + v.y * v.y;
            #pragma unroll
            for (int off = 1; off < 64; off <<= 1) ss += __shfl_xor(ss, off);
            float rn = 1.0f / fmaxf(sqrtf(ss), 1e-12f);
            unsigned int pk = (unsigned)f2bf(v.x * rn) | ((unsigned)f2bf(v.y * rn) << 16);
            Knb[(size_t)row * 64 + lane] = pk;
            if (lane == 0) {
                rnK[row] = rn;
                out[row] = initial[row];
                head_of[row] = 0x7FFFFFFF;
            }
        }
    }

    if (blockIdx.x < (NJ >> 2)) {
        int j = blockIdx.x * 4 + wave;
        int c = j >> 2, s = j & 3;
        const float* base = Theta + (size_t)c * (D_DIM * H_DIM) + s;
        float t0 = base[(2 * lane) * H_DIM];
        float t1 = base[(2 * lane + 1) * H_DIM];
        float ss = t0 * t0 + t1 * t1;
        #pragma unroll
        for (int off = 1; off < 64; off <<= 1) ss += __shfl_xor(ss, off);
        float rn = 1.0f / fmaxf(sqrtf(ss), 1e-12f);
        float n0 = t0 * rn, n1 = t1 * rn;
        Tnb[(size_t)j * 64 + lane] = (unsigned)f2bf(n0) | ((unsigned)f2bf(n1) << 16);
        float2 w; w.x = n0; w.y = n1;
        ((float2*)(Tn32 + (size_t)j * D_DIM))[lane] = w;
    }
}

// ---- bf16 MFMA GEMM, fused per-(j, 32p-chunk) max; XCD-swizzled 1D grid ----
// grid = NT*16 blocks.  Also folds the head_of scatter (block 0).
__global__ __launch_bounds__(256) void k_mfma_max(
    const unsigned short* __restrict__ Knb, const unsigned short* __restrict__ Tnb,
    float* __restrict__ pv2, const int* __restrict__ head_idx,
    int* __restrict__ head_of, int C, int NT4, int NBLK)
{
    __shared__ __align__(16) unsigned short As[128 * 128];  // Tn tile  32 KB
    __shared__ __align__(16) unsigned short Bs[128 * 128];  // Kn tile  32 KB

    int tid = threadIdx.x;
    int orig = blockIdx.x;
    if (orig == 0) {
        for (int g = tid; g < C; g += 256) atomicMin(&head_of[head_idx[g]], g);
    }
    // bijective XCD swizzle: each XCD gets a contiguous wgid range; wgid = p*16 + j
    int q = NBLK >> 3, r = NBLK & 7;
    int xcd = orig & 7, idx = orig >> 3;
    int wgid = (xcd < r ? xcd * (q + 1) : r * (q + 1) + (xcd - r) * q) + idx;
    int pt = wgid >> 4, jt = wgid & 15;
    int p0 = pt * 128, j0 = jt * 128;
    int lane = tid & 63;
    int wave = tid >> 6;

    // stage via global_load_lds: linear LDS dest, inverse-XOR-swizzled global src.
    {
        int rr = lane >> 4, cc = lane & 15;
        const unsigned short* gA = Tnb + (size_t)j0 * 128;
        const unsigned short* gB = Knb + (size_t)p0 * 128;
        #pragma unroll
        for (int i = 0; i < 8; i++) {
            int r0 = wave * 32 + i * 4;
            int rw = r0 + rr;
            int sc = (cc ^ (rw & 7)) << 3;
            __builtin_amdgcn_global_load_lds(
                (const __attribute__((address_space(1))) unsigned int*)(gA + (size_t)rw * 128 + sc),
                (__attribute__((address_space(3))) unsigned int*)&As[r0 * 128], 16, 0, 0);
            __builtin_amdgcn_global_load_lds(
                (const __attribute__((address_space(1))) unsigned int*)(gB + (size_t)rw * 128 + sc),
                (__attribute__((address_space(3))) unsigned int*)&Bs[r0 * 128], 16, 0, 0);
        }
    }
    __syncthreads();

    int wm = wave >> 1, wn = wave & 1;
    int lr = lane & 15, lg = lane >> 4;

    f32x4 acc[4][4];
    #pragma unroll
    for (int m = 0; m < 4; m++)
        #pragma unroll
        for (int n = 0; n < 4; n++) { f32x4 z = {0.f, 0.f, 0.f, 0.f}; acc[m][n] = z; }

    #pragma unroll
    for (int ks = 0; ks < 4; ks++) {
        int koff = (8 * lg + 32 * ks) ^ ((lr & 7) << 3);
        bf16x8v af[4], bv[4];
        #pragma unroll
        for (int m = 0; m < 4; m++) {
            int row = 64 * wm + 16 * m + lr;
            af[m] = *(const bf16x8v*)&As[row * 128 + koff];
        }
        #pragma unroll
        for (int n = 0; n < 4; n++) {
            int row = 64 * wn + 16 * n + lr;
            bv[n] = *(const bf16x8v*)&Bs[row * 128 + koff];
        }
        #pragma unroll
        for (int m = 0; m < 4; m++)
            #pragma unroll
            for (int n = 0; n < 4; n++)
                acc[m][n] = __builtin_amdgcn_mfma_f32_16x16x32_bf16(af[m], bv[n], acc[m][n], 0, 0, 0);
    }

    // epilogue: per-32p-chunk max.  C/D: col(p)=lane&15, row(j)=4*(lane>>4)+reg
    __syncthreads();
    float* red = (float*)As;   // [128 j][4 chunk]
    #pragma unroll
    for (int m = 0; m < 4; m++) {
        #pragma unroll
        for (int n2 = 0; n2 < 2; n2++) {
            f32x4 a0 = acc[m][2 * n2], a1 = acc[m][2 * n2 + 1];
            float t0 = fmaxf(a0[0], a1[0]);
            float t1 = fmaxf(a0[1], a1[1]);
            float t2 = fmaxf(a0[2], a1[2]);
            float t3 = fmaxf(a0[3], a1[3]);
            #pragma unroll
            for (int off = 1; off <= 8; off <<= 1) {
                t0 = fmaxf(t0, __shfl_xor(t0, off));
                t1 = fmaxf(t1, __shfl_xor(t1, off));
                t2 = fmaxf(t2, __shfl_xor(t2, off));
                t3 = fmaxf(t3, __shfl_xor(t3, off));
            }
            if (lr == 0) {
                int jb = 64 * wm + 16 * m + 4 * lg;
                int ch = 2 * wn + n2;
                red[(jb + 0) * 4 + ch] = t0;
                red[(jb + 1) * 4 + ch] = t1;
                red[(jb + 2) * 4 + ch] = t2;
                red[(jb + 3) * 4 + ch] = t3;
            }
        }
    }
    __syncthreads();
    #pragma unroll
    for (int e = tid; e < 512; e += 256) {
        int jl = e >> 2, ch = e & 3;
        pv2[(size_t)(j0 + jl) * NT4 + pt * 4 + ch] = red[jl * 4 + ch];
    }
}

// ---- fused threshold + prune + exact fp32 rescore: one wave per j, no atomics ----
__global__ __launch_bounds__(256) void k_prune(
    const float* __restrict__ pv2, const float* __restrict__ K,
    const float* __restrict__ rnK, const float* __restrict__ Tn32,
    float* __restrict__ conf, int* __restrict__ best, int P, int NT4)
{
    int wave = threadIdx.x >> 6, lane = threadIdx.x & 63;
    int j = blockIdx.x * 4 + wave;
    const float* row = pv2 + (size_t)j * NT4;

    // single pass: load all chunk maxes (NT4=628 <= 640) and reduce
    float v[10];
    float m = -INFINITY;
    #pragma unroll
    for (int i = 0; i < 10; i++) {
        int t = lane + i * 64;
        v[i] = (t < NT4) ? row[t] : -INFINITY;
        m = fmaxf(m, v[i]);
    }
    #pragma unroll
    for (int off = 32; off; off >>= 1) m = fmaxf(m, __shfl_xor(m, off));
    float thr = m - 0.009f;   // 2*eps bf16 unit-vector dot bound

    float bv = -INFINITY; int bbp = 0x7FFFFFFF;
    int half = lane & 1;      // which 64-elem half of the d-dim
    int pl = lane >> 1;       // p within chunk (0..31)
    #pragma unroll
    for (int i = 0; i < 10; i++) {
        unsigned long long ball = __ballot(v[i] >= thr);   // wave-uniform
        while (ball) {
            int bit = __ffsll(ball) - 1;
            ball &= ball - 1;
            int t = i * 64 + bit;
            int p = t * 32 + pl;
            bool ok = (p < P);
            int pc = ok ? p : 0;
            const float4* kp = (const float4*)(K + (size_t)pc * D_DIM + half * 64);
            const float4* tp = (const float4*)(Tn32 + (size_t)j * D_DIM + half * 64);
            float sx = 0.f, sy = 0.f, sz = 0.f, sw = 0.f;
            #pragma unroll
            for (int k4 = 0; k4 < 16; k4++) {
                float4 a = kp[k4], b = tp[k4];
                sx = fmaf(a.x, b.x, sx); sy = fmaf(a.y, b.y, sy);
                sz = fmaf(a.z, b.z, sz); sw = fmaf(a.w, b.w, sw);
            }
            float dot = (sx + sy) + (sz + sw);
            dot += __shfl_xor(dot, 1);      // combine d-halves
            float vv = ok ? dot * rnK[pc] : -INFINITY;
            int bp = p;
            #pragma unroll
            for (int off = 2; off < 64; off <<= 1) {
                float ov = __shfl_xor(vv, off);
                int op = __shfl_xor(bp, off);
                if (ov > vv || (ov == vv && op < bp)) { vv = ov; bp = op; }
            }
            if (vv > bv || (vv == bv && bp < bbp)) { bv = vv; bbp = bp; }
        }
    }
    if (lane == 0) { conf[j] = bv; best[j] = bbp; }
}

// ---- 6-iteration soft-logic loop, single block ----
__global__ __launch_bounds__(1024) void k_logic(
    const int* __restrict__ head_idx, const float* __restrict__ initial_val,
    const float* __restrict__ conf, const int* __restrict__ best,
    const int* __restrict__ head_of,
    float* __restrict__ out, int C)
{
    __shared__ float hval[1024];
    __shared__ float elds[1024];
    int c = threadIdx.x;   // blockDim.x == C
    int h = head_idx[c];
    int myslot = head_of[h];           // min clause index sharing this head
    hval[c] = initial_val[h];

    float cf[H_DIM], v0[H_DIM]; int bs[H_DIM];
    #pragma unroll
    for (int s = 0; s < H_DIM; s++) {
        int b = best[c * H_DIM + s];
        cf[s] = conf[c * H_DIM + s];
        v0[s] = initial_val[b];
        int ho = head_of[b];
        bs[s] = (ho < C) ? ho : -1;
    }
    __syncthreads();

    const float inv_tau = 20.0f;            // 1/TAU
    const float logn = logf(2.0f * H_DIM);  // log 8
    const float beta = 8.0f;

    for (int it = 0; it < 6; it++) {
        float x[2 * H_DIM];
        #pragma unroll
        for (int s = 0; s < H_DIM; s++) {
            x[s] = cf[s];
            x[H_DIM + s] = (bs[s] >= 0) ? hval[bs[s]] : v0[s];
        }
        float cur = hval[myslot];
        elds[c] = 0.f;
        __syncthreads();

        float m = x[0];
        #pragma unroll
        for (int i = 1; i < 2 * H_DIM; i++) m = fminf(m, x[i]);
        float ssum = 0.f;
        #pragma unroll
        for (int i = 0; i < 2 * H_DIM; i++) ssum += expf((m - x[i]) * inv_tau);
        float g = -inv_tau * ((-m * inv_tau + logf(ssum)) - logn);
        g = fminf(fmaxf(g, 0.f), 1.f);
        float w = expf(beta * g);
        atomicAdd(&elds[myslot], w);
        __syncthreads();

        float e = elds[myslot];
        float gh = logf(fmaxf(e, 1e-38f)) / beta;
        float nv = fmaxf(cur, gh);
        if (myslot == c) hval[c] = nv;
        __syncthreads();
    }

    if (myslot == c) out[h] = hval[c];
}

// ---------------- launch ----------------
extern "C" void kernel_launch(void* const* d_in, const int* in_sizes, int n_in,
                              void* d_out, int out_size, void* d_ws, size_t ws_size,
                              hipStream_t stream) {
    const float* K        = (const float*)d_in[0];
    const float* Theta    = (const float*)d_in[1];
    const int*   head_idx = (const int*)d_in[2];
    const float* initial  = (const float*)d_in[3];
    float* out = (float*)d_out;

    int P  = in_sizes[3];
    int C  = in_sizes[2];
    int NJ = C * H_DIM;                     // 2048
    int Ppad = ((P + 127) / 128) * 128;     // 20096
    int NT = Ppad / 128;                    // 157
    int NT4 = NT * 4;                       // 628 (32-p chunks)
    int NBLK = NT * (NJ / 128);             // 2512

    char* w = (char*)d_ws;
    size_t off = 0;
    auto alloc = [&](size_t bytes) { void* p = w + off; off += (bytes + 255) & ~(size_t)255; return p; };
    unsigned int* Knb  = (unsigned int*)alloc((size_t)Ppad * D_DIM * 2);
    unsigned int* Tnb  = (unsigned int*)alloc((size_t)NJ * D_DIM * 2);
    float* Tn32 = (float*)alloc((size_t)NJ * D_DIM * 4);
    float* rnK  = (float*)alloc((size_t)P * 4);
    float* pv2  = (float*)alloc((size_t)NJ * NT4 * 4);
    float* conf = (float*)alloc((size_t)NJ * 4);
    int*   best = (int*)alloc((size_t)NJ * 4);
    int* head_of = (int*)alloc((size_t)P * 4);
    (void)ws_size;

    k_prep<<<Ppad / 4, 256, 0, stream>>>(K, Knb, rnK, Theta, Tnb, Tn32,
                                         initial, out, head_of, P, Ppad, NJ);

    k_mfma_max<<<NBLK, 256, 0, stream>>>((const unsigned short*)Knb,
                                         (const unsigned short*)Tnb, pv2,
                                         head_idx, head_of, C, NT4, NBLK);

    k_prune<<<NJ / 4, 256, 0, stream>>>(pv2, K, rnK, Tn32, conf, best, P, NT4);
    k_logic<<<1, C, 0, stream>>>(head_idx, initial, conf, best, head_of, out, C);
}